// Round 1
// baseline (559.626 us; speedup 1.0000x reference)
//
#include <hip/hip_runtime.h>

#define NB   64
#define NT   30
#define NBT  1920        // NB*NT
#define EE   128
#define KP   28224       // 4*84*84
#define LTK  89          // 3*NT-1
#define NS   5696        // NB*LTK
#define NLY  6
#define NV   18
#define LL4  512

typedef unsigned short ushort_t;
using bf16x8 = __attribute__((ext_vector_type(8))) short;
using us8    = __attribute__((ext_vector_type(8))) unsigned short;
using f32x4  = __attribute__((ext_vector_type(4))) float;

__device__ inline ushort_t f2bf(float f){
  union { float f; unsigned u; } v; v.f = f;
  unsigned r = v.u + 0x7FFFu + ((v.u >> 16) & 1u);   // RNE
  return (ushort_t)(r >> 16);
}

// ---------------- weight fp32 -> bf16 conversion (7 segments, 1 launch) ----
__global__ __launch_bounds__(256) void wcvt(
  const float* conv, const float* Wq, const float* Wk, const float* Wv,
  const float* Wo, const float* W1, const float* W2,
  ushort_t* dc, ushort_t* dq, ushort_t* dk, ushort_t* dv,
  ushort_t* dout, ushort_t* d1, ushort_t* d2)
{
  long i = 4l*((long)blockIdx.x*256 + threadIdx.x);
  const float* s; ushort_t* d; long off;
  if      (i < 3612672l){ s=conv; d=dc;   off=i; }
  else if (i < 3710976l){ s=Wq;   d=dq;   off=i-3612672l; }
  else if (i < 3809280l){ s=Wk;   d=dk;   off=i-3710976l; }
  else if (i < 3907584l){ s=Wv;   d=dv;   off=i-3809280l; }
  else if (i < 4005888l){ s=Wo;   d=dout; off=i-3907584l; }
  else if (i < 4399104l){ s=W1;   d=d1;   off=i-4005888l; }
  else                  { s=W2;   d=d2;   off=i-4399104l; }
  float4 f = *reinterpret_cast<const float4*>(s+off);
  d[off]=f2bf(f.x); d[off+1]=f2bf(f.y); d[off+2]=f2bf(f.z); d[off+3]=f2bf(f.w);
}

// ---------------- inner-TIT weight transposes (k-major for coalescing) -----
__global__ __launch_bounds__(256) void tinner(
  const float* in_w, const float* out_w, const float* f1w, const float* f2w,
  float* t_in, float* t_out, float* t_f1, float* t_f2)
{
  int idx = blockIdx.x*256 + threadIdx.x;
  if (idx < 384*128){ int j=idx>>7, k=idx&127; t_in[k*384+j]=in_w[idx]; }
  if (idx < 128*128){ int j=idx>>7, k=idx&127;
    t_out[k*128+j]=out_w[idx]; t_f1[k*128+j]=f1w[idx]; t_f2[k*128+j]=f2w[idx]; }
}

// ---------------- patch embed: (1920x28224)x(128x28224)^T, split-K atomics -
__global__ __launch_bounds__(256) void patch_gemm(
  const float* __restrict__ A, const ushort_t* __restrict__ Wb, float* __restrict__ C)
{
  __shared__ __align__(16) ushort_t As[32*64];
  __shared__ __align__(16) ushort_t Ws[128*64];
  const int tid = threadIdx.x, lane = tid & 63, wid = tid >> 6;
  const int wr = wid & 1, wc = wid >> 1;
  const int m0 = blockIdx.x * 32;
  const int kbase = blockIdx.z * 1344;
  f32x4 acc[4];
  #pragma unroll
  for (int j=0;j<4;j++) acc[j] = (f32x4){0.f,0.f,0.f,0.f};

  for (int kt = 0; kt < 21; ++kt){
    int k0 = kbase + kt*64;
    { // stage A (32x64 fp32 -> bf16)
      int r = tid >> 3, kq = (tid & 7) * 8;
      const float* src = A + (size_t)(m0+r)*KP + k0 + kq;
      float4 f0 = *reinterpret_cast<const float4*>(src);
      float4 f1 = *reinterpret_cast<const float4*>(src+4);
      us8 o;
      o[0]=f2bf(f0.x); o[1]=f2bf(f0.y); o[2]=f2bf(f0.z); o[3]=f2bf(f0.w);
      o[4]=f2bf(f1.x); o[5]=f2bf(f1.y); o[6]=f2bf(f1.z); o[7]=f2bf(f1.w);
      *reinterpret_cast<us8*>(&As[r*64 + (kq ^ ((r&7)<<3))]) = o;
    }
    #pragma unroll
    for (int i=0;i<4;i++){ // stage W (128x64 bf16)
      int rr = (tid>>3) + 32*i, kq = (tid & 7) * 8;
      us8 v = *reinterpret_cast<const us8*>(Wb + (size_t)rr*KP + k0 + kq);
      *reinterpret_cast<us8*>(&Ws[rr*64 + (kq ^ ((rr&7)<<3))]) = v;
    }
    __syncthreads();
    #pragma unroll
    for (int ks=0; ks<2; ++ks){
      int ar = wr*16 + (lane&15);
      int kb = ks*32 + (lane>>4)*8;
      bf16x8 a = *reinterpret_cast<const bf16x8*>(&As[ar*64 + (kb ^ ((ar&7)<<3))]);
      #pragma unroll
      for (int j=0;j<4;j++){
        int nn = wc*64 + j*16 + (lane&15);
        bf16x8 b = *reinterpret_cast<const bf16x8*>(&Ws[nn*64 + (kb ^ ((nn&7)<<3))]);
        acc[j] = __builtin_amdgcn_mfma_f32_16x16x32_bf16(a, b, acc[j], 0,0,0);
      }
    }
    __syncthreads();
  }
  #pragma unroll
  for (int j=0;j<4;j++)
    #pragma unroll
    for (int rr=0;rr<4;rr++){
      int row = m0 + wr*16 + (lane>>4)*4 + rr;
      int col = wc*64 + j*16 + (lane&15);
      atomicAdd(&C[row*EE + col], acc[j][rr]);
    }
}

// ---------------- generic bf16-MFMA GEMM: C = act(LN?(A) @ W^T + bias)[+res]
template<int K, bool ABF, bool LN, int ACT, bool RES, bool OBF>
__global__ __launch_bounds__(256) void gemm_k(
  const void* __restrict__ Ap, const ushort_t* __restrict__ W,
  const float* __restrict__ bias, const float* __restrict__ lng,
  const float* __restrict__ lnb, float* __restrict__ Co,
  ushort_t* __restrict__ Cob, const float* __restrict__ resid, int N)
{
  __shared__ __align__(16) ushort_t As[32*128];
  __shared__ __align__(16) ushort_t Ws[128*128];
  const int tid = threadIdx.x, lane = tid & 63, wid = tid >> 6;
  const int wr = wid & 1, wc = wid >> 1;
  const int m0 = blockIdx.x * 32;
  const int n0 = blockIdx.y * 128;
  const int r = tid >> 3, kq = (tid & 7) * 16;
  f32x4 acc[4];
  #pragma unroll
  for (int j=0;j<4;j++) acc[j] = (f32x4){0.f,0.f,0.f,0.f};

  #pragma unroll
  for (int kc = 0; kc < K/128; ++kc){
    // ---- stage A ----
    if constexpr (LN){   // K==128, fused LayerNorm during staging
      const float* src = (const float*)Ap + (size_t)(m0+r)*K + kq;
      float xv[16];
      #pragma unroll
      for (int i=0;i<4;i++){
        float4 f = *reinterpret_cast<const float4*>(src + 4*i);
        xv[4*i]=f.x; xv[4*i+1]=f.y; xv[4*i+2]=f.z; xv[4*i+3]=f.w;
      }
      float s = 0;
      #pragma unroll
      for (int i=0;i<16;i++) s += xv[i];
      s += __shfl_xor(s,1); s += __shfl_xor(s,2); s += __shfl_xor(s,4);
      float mean = s * (1.0f/128.0f);
      float vs = 0;
      #pragma unroll
      for (int i=0;i<16;i++){ float d = xv[i]-mean; vs += d*d; }
      vs += __shfl_xor(vs,1); vs += __shfl_xor(vs,2); vs += __shfl_xor(vs,4);
      float rstd = rsqrtf(vs*(1.0f/128.0f) + 1e-5f);
      us8 o0, o1;
      #pragma unroll
      for (int i=0;i<8;i++){
        o0[i] = f2bf((xv[i]  -mean)*rstd*lng[kq+i]  +lnb[kq+i]);
        o1[i] = f2bf((xv[8+i]-mean)*rstd*lng[kq+8+i]+lnb[kq+8+i]);
      }
      int sw = (r&7)<<3;
      *reinterpret_cast<us8*>(&As[r*128 + ( kq    ^ sw)]) = o0;
      *reinterpret_cast<us8*>(&As[r*128 + ((kq+8) ^ sw)]) = o1;
    } else if constexpr (ABF){
      const ushort_t* src = (const ushort_t*)Ap + (size_t)(m0+r)*K + kc*128 + kq;
      us8 v0 = *reinterpret_cast<const us8*>(src);
      us8 v1 = *reinterpret_cast<const us8*>(src+8);
      int sw = (r&7)<<3;
      *reinterpret_cast<us8*>(&As[r*128 + ( kq    ^ sw)]) = v0;
      *reinterpret_cast<us8*>(&As[r*128 + ((kq+8) ^ sw)]) = v1;
    } else {
      const float* src = (const float*)Ap + (size_t)(m0+r)*K + kc*128 + kq;
      us8 o0, o1;
      #pragma unroll
      for (int i=0;i<4;i++){
        float4 f = *reinterpret_cast<const float4*>(src + 4*i);
        ushort_t a0=f2bf(f.x), a1=f2bf(f.y), a2=f2bf(f.z), a3=f2bf(f.w);
        if (i<2){ o0[4*i]=a0; o0[4*i+1]=a1; o0[4*i+2]=a2; o0[4*i+3]=a3; }
        else    { o1[4*(i-2)]=a0; o1[4*(i-2)+1]=a1; o1[4*(i-2)+2]=a2; o1[4*(i-2)+3]=a3; }
      }
      int sw = (r&7)<<3;
      *reinterpret_cast<us8*>(&As[r*128 + ( kq    ^ sw)]) = o0;
      *reinterpret_cast<us8*>(&As[r*128 + ((kq+8) ^ sw)]) = o1;
    }
    // ---- stage W ----
    #pragma unroll
    for (int i=0;i<4;i++){
      int rr = (tid>>3) + 32*i;
      const ushort_t* src = W + (size_t)(n0+rr)*K + kc*128 + kq;
      us8 v0 = *reinterpret_cast<const us8*>(src);
      us8 v1 = *reinterpret_cast<const us8*>(src+8);
      int sw = (rr&7)<<3;
      *reinterpret_cast<us8*>(&Ws[rr*128 + ( kq    ^ sw)]) = v0;
      *reinterpret_cast<us8*>(&Ws[rr*128 + ((kq+8) ^ sw)]) = v1;
    }
    __syncthreads();
    #pragma unroll
    for (int ks=0; ks<4; ++ks){
      int ar = wr*16 + (lane&15);
      int kb = ks*32 + (lane>>4)*8;
      bf16x8 a = *reinterpret_cast<const bf16x8*>(&As[ar*128 + (kb ^ ((ar&7)<<3))]);
      #pragma unroll
      for (int j=0;j<4;j++){
        int nn = wc*64 + j*16 + (lane&15);
        bf16x8 b = *reinterpret_cast<const bf16x8*>(&Ws[nn*128 + (kb ^ ((nn&7)<<3))]);
        acc[j] = __builtin_amdgcn_mfma_f32_16x16x32_bf16(a, b, acc[j], 0,0,0);
      }
    }
    __syncthreads();
  }
  #pragma unroll
  for (int j=0;j<4;j++)
    #pragma unroll
    for (int rr=0;rr<4;rr++){
      int row = m0 + wr*16 + (lane>>4)*4 + rr;
      int col = n0 + wc*64 + j*16 + (lane&15);
      float v = acc[j][rr] + bias[col];
      if constexpr (ACT==1) v = 0.5f*v*(1.0f + erff(v*0.70710678118654752f));
      if constexpr (RES)    v += resid[(size_t)row*N + col];
      if constexpr (OBF)    Cob[(size_t)row*N + col] = f2bf(v);
      else                  Co [(size_t)row*N + col] = v;
    }
}

// ---------------- block-of-128 reduction helper ----------------------------
__device__ inline float bsum128(float v, volatile float* red){
  v += __shfl_xor(v,1);  v += __shfl_xor(v,2);  v += __shfl_xor(v,4);
  v += __shfl_xor(v,8);  v += __shfl_xor(v,16); v += __shfl_xor(v,32);
  int tid = threadIdx.x;
  if ((tid & 63) == 0) red[tid>>6] = v;
  __syncthreads();
  float s = red[0] + red[1];
  __syncthreads();
  return s;
}

// ---------------- inner TIT (one block per bt, 128 threads) ----------------
__global__ __launch_bounds__(128) void inner_tit(
  const float* __restrict__ patch, const float* __restrict__ ctok,
  const float* __restrict__ t_in, const float* __restrict__ in_b,
  const float* __restrict__ t_out, const float* __restrict__ out_b,
  const float* __restrict__ g1, const float* __restrict__ b1_,
  const float* __restrict__ g2, const float* __restrict__ b2_,
  const float* __restrict__ t_f1, const float* __restrict__ fb1,
  const float* __restrict__ t_f2, const float* __restrict__ fb2,
  float* __restrict__ semb)
{
  int bt = blockIdx.x, e = threadIdx.x;
  __shared__ float xs[2][128], hs[2][128], qs[2][128], ks2[2][128], vs[2][128];
  __shared__ float red[2];
  xs[0][e] = ctok[e];
  xs[1][e] = patch[bt*128+e];
  __syncthreads();
  for (int t=0;t<2;t++){             // LN1
    float xv = xs[t][e];
    float m = bsum128(xv, red)*(1.f/128.f);
    float d = xv - m;
    float var = bsum128(d*d, red)*(1.f/128.f);
    hs[t][e] = d*rsqrtf(var+1e-5f)*g1[e] + b1_[e];
  }
  __syncthreads();
  for (int t=0;t<2;t++){             // qkv
    float aq=in_b[e], ak=in_b[128+e], av=in_b[256+e];
    for (int kk=0;kk<128;kk++){
      float h = hs[t][kk];
      aq += h*t_in[kk*384+e]; ak += h*t_in[kk*384+128+e]; av += h*t_in[kk*384+256+e];
    }
    qs[t][e]=aq; ks2[t][e]=ak; vs[t][e]=av;
  }
  __syncthreads();
  const float sc = 0.08838834764831845f;   // 1/sqrt(128)
  float s00 = bsum128(qs[0][e]*ks2[0][e], red)*sc;
  float s01 = bsum128(qs[0][e]*ks2[1][e], red)*sc;
  float s10 = bsum128(qs[1][e]*ks2[0][e], red)*sc;
  float s11 = bsum128(qs[1][e]*ks2[1][e], red)*sc;
  {
    float m0 = fmaxf(s00,s01), p0=expf(s00-m0), p1=expf(s01-m0), iv=1.f/(p0+p1);
    hs[0][e] = (p0*vs[0][e] + p1*vs[1][e])*iv;
    float m1 = fmaxf(s10,s11), r0=expf(s10-m1), r1=expf(s11-m1), iw=1.f/(r0+r1);
    hs[1][e] = (r0*vs[0][e] + r1*vs[1][e])*iw;
  }
  __syncthreads();
  for (int t=0;t<2;t++){             // out-proj + residual
    float o = out_b[e];
    for (int kk=0;kk<128;kk++) o += hs[t][kk]*t_out[kk*128+e];
    xs[t][e] += o;
  }
  __syncthreads();
  for (int t=0;t<2;t++){             // LN2 -> qs
    float xv = xs[t][e];
    float m = bsum128(xv, red)*(1.f/128.f);
    float d = xv - m;
    float var = bsum128(d*d, red)*(1.f/128.f);
    qs[t][e] = d*rsqrtf(var+1e-5f)*g2[e] + b2_[e];
  }
  __syncthreads();
  for (int t=0;t<2;t++){             // FFN1 (relu) -> hs
    float a = fb1[e];
    for (int kk=0;kk<128;kk++) a += qs[t][kk]*t_f1[kk*128+e];
    hs[t][e] = fmaxf(a, 0.f);
  }
  __syncthreads();
  for (int t=0;t<2;t++){             // FFN2 + residual
    float a = fb2[e];
    for (int kk=0;kk<128;kk++) a += hs[t][kk]*t_f2[kk*128+e];
    xs[t][e] += a;
  }
  semb[bt*128+e] = xs[0][e];
}

// ---------------- token interleave + positional ----------------------------
__global__ __launch_bounds__(256) void build_tok(
  const float* __restrict__ semb, const float* __restrict__ rtgs,
  const int* __restrict__ actions, const int* __restrict__ tsteps,
  const float* __restrict__ ret_w, const float* __restrict__ ret_b,
  const float* __restrict__ act_tab, const float* __restrict__ pos_emb,
  const float* __restrict__ gpos, float* __restrict__ x)
{
  int idx = blockIdx.x*256 + threadIdx.x;
  if (idx >= NS*EE) return;
  int e = idx & 127, s = idx >> 7;
  int b = s / LTK, p = s - b*LTK;
  int t = p/3, m = p - 3*t;
  float tok;
  if      (m == 0) tok = tanhf(rtgs[b*NT+t]*ret_w[e] + ret_b[e]);
  else if (m == 1) tok = semb[(b*NT+t)*128 + e];
  else             tok = tanhf(act_tab[actions[b*NT+t+1]*128 + e]);
  x[idx] = tok + gpos[(size_t)tsteps[b]*128 + e] + pos_emb[p*128 + e];
}

// ---------------- outer causal attention: one block per (b,h) --------------
__global__ __launch_bounds__(128) void attn_k(
  const float* __restrict__ q, const float* __restrict__ k,
  const float* __restrict__ v, ushort_t* __restrict__ y)
{
  __shared__ float qs[LTK][16], ks[LTK][16], vs[LTK][16];
  __shared__ float ps[LTK][91];          // pad 91 to kill bank conflicts
  int b = blockIdx.x >> 3, h = blockIdx.x & 7;
  int tid = threadIdx.x;
  for (int i = tid; i < LTK*16; i += 128){
    int rr = i >> 4, d = i & 15;
    size_t g = (size_t)(b*LTK+rr)*128 + h*16 + d;
    qs[rr][d]=q[g]; ks[rr][d]=k[g]; vs[rr][d]=v[g];
  }
  __syncthreads();
  int t = tid;
  if (t < LTK){
    float qr[16];
    #pragma unroll
    for (int d=0;d<16;d++) qr[d]=qs[t][d];
    float mx = -1e30f;
    for (int u=0; u<=t; ++u){
      float s = 0;
      #pragma unroll
      for (int d=0;d<16;d++) s += qr[d]*ks[u][d];
      s *= 0.25f;                         // 1/sqrt(16)
      ps[t][u] = s; mx = fmaxf(mx, s);
    }
    float l = 0;
    for (int u=0; u<=t; ++u){ float p = expf(ps[t][u]-mx); ps[t][u]=p; l+=p; }
    float iv = 1.0f/l;
    #pragma unroll
    for (int d=0; d<16; ++d){
      float a = 0;
      for (int u=0; u<=t; ++u) a += ps[t][u]*vs[u][d];
      y[(size_t)(b*LTK+t)*128 + h*16 + d] = f2bf(a*iv);
    }
  }
}

// ---------------- final LN + head on the 1920 state tokens -----------------
__global__ __launch_bounds__(128) void head_k(
  const float* __restrict__ x, const float* __restrict__ g,
  const float* __restrict__ bb, const float* __restrict__ hw,
  float* __restrict__ out)
{
  __shared__ float red[2];
  int bt = blockIdx.x;
  int b = bt/NT, t = bt - b*NT;
  int e = threadIdx.x;
  const float* row = x + (size_t)(b*LTK + 3*t + 1)*128;
  float xv = row[e];
  float m = bsum128(xv, red)*(1.f/128.f);
  float d = xv - m;
  float var = bsum128(d*d, red)*(1.f/128.f);
  float h = d*rsqrtf(var+1e-5f)*g[e] + bb[e];
  for (int o=0;o<NV;o++){
    float s = bsum128(h*hw[o*128+e], red);
    if (e == 0) out[(size_t)(b*NT+t)*NV + o] = s;
  }
}

// ===========================================================================
extern "C" void kernel_launch(void* const* d_in, const int* in_sizes, int n_in,
                              void* d_out, int out_size, void* d_ws, size_t ws_size,
                              hipStream_t stream)
{
  const float* states  = (const float*)d_in[0];
  const int*   actions = (const int*)  d_in[1];
  const float* rtgs    = (const float*)d_in[2];
  const int*   tsteps  = (const int*)  d_in[3];
  const float* conv_w  = (const float*)d_in[4];
  const float* ctok    = (const float*)d_in[5];
  const float* in_w    = (const float*)d_in[6];
  const float* in_b    = (const float*)d_in[7];
  const float* out_w   = (const float*)d_in[8];
  const float* out_b   = (const float*)d_in[9];
  const float* i1g     = (const float*)d_in[10];
  const float* i1b     = (const float*)d_in[11];
  const float* i2g     = (const float*)d_in[12];
  const float* i2b     = (const float*)d_in[13];
  const float* fw1     = (const float*)d_in[14];
  const float* fb1     = (const float*)d_in[15];
  const float* fw2     = (const float*)d_in[16];
  const float* fb2     = (const float*)d_in[17];
  const float* ret_w   = (const float*)d_in[18];
  const float* ret_b   = (const float*)d_in[19];
  const float* act_tab = (const float*)d_in[20];
  const float* pos_emb = (const float*)d_in[21];
  const float* gpos    = (const float*)d_in[22];
  const float* ln1g    = (const float*)d_in[23];
  const float* ln1b    = (const float*)d_in[24];
  const float* Wq      = (const float*)d_in[25];
  const float* bq      = (const float*)d_in[26];
  const float* Wk      = (const float*)d_in[27];
  const float* bk      = (const float*)d_in[28];
  const float* Wv      = (const float*)d_in[29];
  const float* bv      = (const float*)d_in[30];
  const float* Wo      = (const float*)d_in[31];
  const float* bo      = (const float*)d_in[32];
  const float* ln2g    = (const float*)d_in[33];
  const float* ln2b    = (const float*)d_in[34];
  const float* W1      = (const float*)d_in[35];
  const float* b1      = (const float*)d_in[36];
  const float* W2      = (const float*)d_in[37];
  const float* b2      = (const float*)d_in[38];
  const float* lnfg    = (const float*)d_in[39];
  const float* lnfb    = (const float*)d_in[40];
  const float* head_w  = (const float*)d_in[41];

  char* w = (char*)d_ws;
  size_t off = 0;
  auto alloc = [&](size_t bytes)->char* {
    char* p = w + off; off += (bytes + 255) & ~(size_t)255; return p;
  };
  float*    patch = (float*)   alloc((size_t)NBT*EE*4);
  float*    semb  = (float*)   alloc((size_t)NBT*EE*4);
  float*    x     = (float*)   alloc((size_t)NS*EE*4);
  float*    qb    = (float*)   alloc((size_t)NS*EE*4);
  float*    kb    = (float*)   alloc((size_t)NS*EE*4);
  float*    vb    = (float*)   alloc((size_t)NS*EE*4);
  ushort_t* yb    = (ushort_t*)alloc((size_t)NS*EE*2);
  ushort_t* f1b_  = (ushort_t*)alloc((size_t)NS*LL4*2);
  ushort_t* cwb   = (ushort_t*)alloc((size_t)EE*KP*2);
  ushort_t* Wqb   = (ushort_t*)alloc((size_t)NLY*128*128*2);
  ushort_t* Wkb   = (ushort_t*)alloc((size_t)NLY*128*128*2);
  ushort_t* Wvb   = (ushort_t*)alloc((size_t)NLY*128*128*2);
  ushort_t* Wob   = (ushort_t*)alloc((size_t)NLY*128*128*2);
  ushort_t* W1b   = (ushort_t*)alloc((size_t)NLY*512*128*2);
  ushort_t* W2b   = (ushort_t*)alloc((size_t)NLY*128*512*2);
  float*    t_in  = (float*)   alloc(384*128*4);
  float*    t_out = (float*)   alloc(128*128*4);
  float*    t_f1  = (float*)   alloc(128*128*4);
  float*    t_f2  = (float*)   alloc(128*128*4);
  (void)in_sizes; (void)n_in; (void)out_size; (void)ws_size;

  wcvt<<<4680,256,0,stream>>>(conv_w,Wq,Wk,Wv,Wo,W1,W2, cwb,Wqb,Wkb,Wvb,Wob,W1b,W2b);
  tinner<<<192,256,0,stream>>>(in_w,out_w,fw1,fw2, t_in,t_out,t_f1,t_f2);
  hipMemsetAsync(patch, 0, (size_t)NBT*EE*4, stream);
  patch_gemm<<<dim3(60,1,21),256,0,stream>>>(states, cwb, patch);
  inner_tit<<<NBT,128,0,stream>>>(patch, ctok, t_in, in_b, t_out, out_b,
                                  i1g,i1b,i2g,i2b, t_f1,fb1, t_f2,fb2, semb);
  build_tok<<<2848,256,0,stream>>>(semb, rtgs, actions, tsteps, ret_w, ret_b,
                                   act_tab, pos_emb, gpos, x);
  for (int i=0;i<NLY;i++){
    gemm_k<128,false,true,0,false,false><<<dim3(178,1),256,0,stream>>>(
      x, Wqb+(size_t)i*16384, bq+i*128, ln1g+i*128, ln1b+i*128, qb, nullptr, nullptr, 128);
    gemm_k<128,false,true,0,false,false><<<dim3(178,1),256,0,stream>>>(
      x, Wkb+(size_t)i*16384, bk+i*128, ln1g+i*128, ln1b+i*128, kb, nullptr, nullptr, 128);
    gemm_k<128,false,true,0,false,false><<<dim3(178,1),256,0,stream>>>(
      x, Wvb+(size_t)i*16384, bv+i*128, ln1g+i*128, ln1b+i*128, vb, nullptr, nullptr, 128);
    attn_k<<<512,128,0,stream>>>(qb,kb,vb,yb);
    gemm_k<128,true,false,0,true,false><<<dim3(178,1),256,0,stream>>>(
      yb, Wob+(size_t)i*16384, bo+i*128, nullptr, nullptr, x, nullptr, x, 128);
    gemm_k<128,false,true,1,false,true><<<dim3(178,4),256,0,stream>>>(
      x, W1b+(size_t)i*65536, b1+i*512, ln2g+i*128, ln2b+i*128, nullptr, f1b_, nullptr, 512);
    gemm_k<512,true,false,0,true,false><<<dim3(178,1),256,0,stream>>>(
      f1b_, W2b+(size_t)i*65536, b2+i*128, nullptr, nullptr, x, nullptr, x, 128);
  }
  head_k<<<NBT,128,0,stream>>>(x, lnfg, lnfb, head_w, (float*)d_out);
}

// Round 2
// 474.849 us; speedup vs baseline: 1.1785x; 1.1785x over previous
//
#include <hip/hip_runtime.h>

#define NB   64
#define NT   30
#define NBT  1920        // NB*NT
#define EE   128
#define KP   28224       // 4*84*84
#define LTK  89          // 3*NT-1
#define NS   5696        // NB*LTK
#define NLY  6
#define NV   18
#define LL4  512
#define NZ   21          // split-K slabs for patch gemm

typedef unsigned short ushort_t;
using bf16x8 = __attribute__((ext_vector_type(8))) short;
using us8    = __attribute__((ext_vector_type(8))) unsigned short;
using f32x4  = __attribute__((ext_vector_type(4))) float;

__device__ inline ushort_t f2bf(float f){
  union { float f; unsigned u; } v; v.f = f;
  unsigned r = v.u + 0x7FFFu + ((v.u >> 16) & 1u);   // RNE
  return (ushort_t)(r >> 16);
}

// ---------------- weight fp32 -> bf16 conversion (1 launch) ----------------
// q/k/v are repacked into a per-layer (384,128) block for the fused QKV gemm.
__global__ __launch_bounds__(256) void wcvt(
  const float* conv, const float* Wq, const float* Wk, const float* Wv,
  const float* Wo, const float* W1, const float* W2,
  ushort_t* dc, ushort_t* dqkv, ushort_t* dout, ushort_t* d1, ushort_t* d2)
{
  long i = 4l*((long)blockIdx.x*256 + threadIdx.x);
  if (i < 3612672l){
    float4 f = *reinterpret_cast<const float4*>(conv+i);
    dc[i]=f2bf(f.x); dc[i+1]=f2bf(f.y); dc[i+2]=f2bf(f.z); dc[i+3]=f2bf(f.w);
    return;
  }
  if (i < 3907584l){                       // Wq | Wk | Wv
    long o = i - 3612672l;
    int  seg = (int)(o / 98304l);
    long off = o - (long)seg*98304l;       // within (NLY,128,128)
    long layer = off >> 14, rem = off & 16383l;
    const float* s = (seg==0) ? Wq : (seg==1) ? Wk : Wv;
    float4 f = *reinterpret_cast<const float4*>(s+off);
    long dst = layer*49152l + (long)seg*16384l + rem;
    dqkv[dst]=f2bf(f.x); dqkv[dst+1]=f2bf(f.y); dqkv[dst+2]=f2bf(f.z); dqkv[dst+3]=f2bf(f.w);
    return;
  }
  const float* s; ushort_t* d; long off;
  if      (i < 4005888l){ s=Wo; d=dout; off=i-3907584l; }
  else if (i < 4399104l){ s=W1; d=d1;   off=i-4005888l; }
  else                  { s=W2; d=d2;   off=i-4399104l; }
  float4 f = *reinterpret_cast<const float4*>(s+off);
  d[off]=f2bf(f.x); d[off+1]=f2bf(f.y); d[off+2]=f2bf(f.z); d[off+3]=f2bf(f.w);
}

// -------- inner-TIT weight transposes + outer qkv bias packing -------------
__global__ __launch_bounds__(256) void tinner(
  const float* in_w, const float* out_w, const float* f1w, const float* f2w,
  const float* bq, const float* bk, const float* bv,
  float* t_in, float* t_out, float* t_f1, float* t_f2, float* bqkv)
{
  int idx = blockIdx.x*256 + threadIdx.x;
  if (idx < 384*128){ int j=idx>>7, k=idx&127; t_in[k*384+j]=in_w[idx]; }
  if (idx < 128*128){ int j=idx>>7, k=idx&127;
    t_out[k*128+j]=out_w[idx]; t_f1[k*128+j]=f1w[idx]; t_f2[k*128+j]=f2w[idx]; }
  if (idx < NLY*128){ int l=idx>>7, j=idx&127;
    bqkv[l*384+j]=bq[idx]; bqkv[l*384+128+j]=bk[idx]; bqkv[l*384+256+j]=bv[idx]; }
}

// ---------------- patch embed: split-K into NZ disjoint slabs --------------
__global__ __launch_bounds__(256) void patch_gemm(
  const float* __restrict__ A, const ushort_t* __restrict__ Wb, float* __restrict__ C)
{
  __shared__ __align__(16) ushort_t As[32*64];
  __shared__ __align__(16) ushort_t Ws[128*64];
  const int tid = threadIdx.x, lane = tid & 63, wid = tid >> 6;
  const int wr = wid & 1, wc = wid >> 1;
  const int m0 = blockIdx.x * 32;
  const int kbase = blockIdx.z * 1344;
  float* Cz = C + (size_t)blockIdx.z * NBT * EE;
  f32x4 acc[4];
  #pragma unroll
  for (int j=0;j<4;j++) acc[j] = (f32x4){0.f,0.f,0.f,0.f};

  for (int kt = 0; kt < 21; ++kt){
    int k0 = kbase + kt*64;
    { // stage A (32x64 fp32 -> bf16)
      int r = tid >> 3, kq = (tid & 7) * 8;
      const float* src = A + (size_t)(m0+r)*KP + k0 + kq;
      float4 f0 = *reinterpret_cast<const float4*>(src);
      float4 f1 = *reinterpret_cast<const float4*>(src+4);
      us8 o;
      o[0]=f2bf(f0.x); o[1]=f2bf(f0.y); o[2]=f2bf(f0.z); o[3]=f2bf(f0.w);
      o[4]=f2bf(f1.x); o[5]=f2bf(f1.y); o[6]=f2bf(f1.z); o[7]=f2bf(f1.w);
      *reinterpret_cast<us8*>(&As[r*64 + (kq ^ ((r&7)<<3))]) = o;
    }
    #pragma unroll
    for (int i=0;i<4;i++){ // stage W (128x64 bf16)
      int rr = (tid>>3) + 32*i, kq = (tid & 7) * 8;
      us8 v = *reinterpret_cast<const us8*>(Wb + (size_t)rr*KP + k0 + kq);
      *reinterpret_cast<us8*>(&Ws[rr*64 + (kq ^ ((rr&7)<<3))]) = v;
    }
    __syncthreads();
    #pragma unroll
    for (int ks=0; ks<2; ++ks){
      int ar = wr*16 + (lane&15);
      int kb = ks*32 + (lane>>4)*8;
      bf16x8 a = *reinterpret_cast<const bf16x8*>(&As[ar*64 + (kb ^ ((ar&7)<<3))]);
      #pragma unroll
      for (int j=0;j<4;j++){
        int nn = wc*64 + j*16 + (lane&15);
        bf16x8 b = *reinterpret_cast<const bf16x8*>(&Ws[nn*64 + (kb ^ ((nn&7)<<3))]);
        acc[j] = __builtin_amdgcn_mfma_f32_16x16x32_bf16(a, b, acc[j], 0,0,0);
      }
    }
    __syncthreads();
  }
  #pragma unroll
  for (int j=0;j<4;j++)
    #pragma unroll
    for (int rr=0;rr<4;rr++){
      int row = m0 + wr*16 + (lane>>4)*4 + rr;
      int col = wc*64 + j*16 + (lane&15);
      Cz[row*EE + col] = acc[j][rr];
    }
}

// ---------------- generic bf16-MFMA GEMM: C = act(LN?(A) @ W^T + bias)[+res]
template<int K, bool ABF, bool LN, int ACT, bool RES, bool OBF>
__global__ __launch_bounds__(256) void gemm_k(
  const void* __restrict__ Ap, const ushort_t* __restrict__ W,
  const float* __restrict__ bias, const float* __restrict__ lng,
  const float* __restrict__ lnb, float* __restrict__ Co,
  ushort_t* __restrict__ Cob, const float* __restrict__ resid, int N)
{
  __shared__ __align__(16) ushort_t As[32*128];
  __shared__ __align__(16) ushort_t Ws[128*128];
  const int tid = threadIdx.x, lane = tid & 63, wid = tid >> 6;
  const int wr = wid & 1, wc = wid >> 1;
  const int m0 = blockIdx.x * 32;
  const int n0 = blockIdx.y * 128;
  const int r = tid >> 3, kq = (tid & 7) * 16;
  f32x4 acc[4];
  #pragma unroll
  for (int j=0;j<4;j++) acc[j] = (f32x4){0.f,0.f,0.f,0.f};

  #pragma unroll
  for (int kc = 0; kc < K/128; ++kc){
    // ---- stage A ----
    if constexpr (LN){   // K==128, fused LayerNorm during staging
      const float* src = (const float*)Ap + (size_t)(m0+r)*K + kq;
      float xv[16];
      #pragma unroll
      for (int i=0;i<4;i++){
        float4 f = *reinterpret_cast<const float4*>(src + 4*i);
        xv[4*i]=f.x; xv[4*i+1]=f.y; xv[4*i+2]=f.z; xv[4*i+3]=f.w;
      }
      float s = 0;
      #pragma unroll
      for (int i=0;i<16;i++) s += xv[i];
      s += __shfl_xor(s,1); s += __shfl_xor(s,2); s += __shfl_xor(s,4);
      float mean = s * (1.0f/128.0f);
      float vs = 0;
      #pragma unroll
      for (int i=0;i<16;i++){ float d = xv[i]-mean; vs += d*d; }
      vs += __shfl_xor(vs,1); vs += __shfl_xor(vs,2); vs += __shfl_xor(vs,4);
      float rstd = rsqrtf(vs*(1.0f/128.0f) + 1e-5f);
      us8 o0, o1;
      #pragma unroll
      for (int i=0;i<8;i++){
        o0[i] = f2bf((xv[i]  -mean)*rstd*lng[kq+i]  +lnb[kq+i]);
        o1[i] = f2bf((xv[8+i]-mean)*rstd*lng[kq+8+i]+lnb[kq+8+i]);
      }
      int sw = (r&7)<<3;
      *reinterpret_cast<us8*>(&As[r*128 + ( kq    ^ sw)]) = o0;
      *reinterpret_cast<us8*>(&As[r*128 + ((kq+8) ^ sw)]) = o1;
    } else if constexpr (ABF){
      const ushort_t* src = (const ushort_t*)Ap + (size_t)(m0+r)*K + kc*128 + kq;
      us8 v0 = *reinterpret_cast<const us8*>(src);
      us8 v1 = *reinterpret_cast<const us8*>(src+8);
      int sw = (r&7)<<3;
      *reinterpret_cast<us8*>(&As[r*128 + ( kq    ^ sw)]) = v0;
      *reinterpret_cast<us8*>(&As[r*128 + ((kq+8) ^ sw)]) = v1;
    } else {
      const float* src = (const float*)Ap + (size_t)(m0+r)*K + kc*128 + kq;
      us8 o0, o1;
      #pragma unroll
      for (int i=0;i<4;i++){
        float4 f = *reinterpret_cast<const float4*>(src + 4*i);
        ushort_t a0=f2bf(f.x), a1=f2bf(f.y), a2=f2bf(f.z), a3=f2bf(f.w);
        if (i<2){ o0[4*i]=a0; o0[4*i+1]=a1; o0[4*i+2]=a2; o0[4*i+3]=a3; }
        else    { o1[4*(i-2)]=a0; o1[4*(i-2)+1]=a1; o1[4*(i-2)+2]=a2; o1[4*(i-2)+3]=a3; }
      }
      int sw = (r&7)<<3;
      *reinterpret_cast<us8*>(&As[r*128 + ( kq    ^ sw)]) = o0;
      *reinterpret_cast<us8*>(&As[r*128 + ((kq+8) ^ sw)]) = o1;
    }
    // ---- stage W ----
    #pragma unroll
    for (int i=0;i<4;i++){
      int rr = (tid>>3) + 32*i;
      const ushort_t* src = W + (size_t)(n0+rr)*K + kc*128 + kq;
      us8 v0 = *reinterpret_cast<const us8*>(src);
      us8 v1 = *reinterpret_cast<const us8*>(src+8);
      int sw = (rr&7)<<3;
      *reinterpret_cast<us8*>(&Ws[rr*128 + ( kq    ^ sw)]) = v0;
      *reinterpret_cast<us8*>(&Ws[rr*128 + ((kq+8) ^ sw)]) = v1;
    }
    __syncthreads();
    #pragma unroll
    for (int ks=0; ks<4; ++ks){
      int ar = wr*16 + (lane&15);
      int kb = ks*32 + (lane>>4)*8;
      bf16x8 a = *reinterpret_cast<const bf16x8*>(&As[ar*128 + (kb ^ ((ar&7)<<3))]);
      #pragma unroll
      for (int j=0;j<4;j++){
        int nn = wc*64 + j*16 + (lane&15);
        bf16x8 b = *reinterpret_cast<const bf16x8*>(&Ws[nn*128 + (kb ^ ((nn&7)<<3))]);
        acc[j] = __builtin_amdgcn_mfma_f32_16x16x32_bf16(a, b, acc[j], 0,0,0);
      }
    }
    __syncthreads();
  }
  #pragma unroll
  for (int j=0;j<4;j++)
    #pragma unroll
    for (int rr=0;rr<4;rr++){
      int row = m0 + wr*16 + (lane>>4)*4 + rr;
      int col = n0 + wc*64 + j*16 + (lane&15);
      float v = acc[j][rr] + bias[col];
      if constexpr (ACT==1) v = 0.5f*v*(1.0f + erff(v*0.70710678118654752f));
      if constexpr (RES)    v += resid[(size_t)row*N + col];
      if constexpr (OBF)    Cob[(size_t)row*N + col] = f2bf(v);
      else                  Co [(size_t)row*N + col] = v;
    }
}

// ---------------- block-of-128 reduction helper ----------------------------
__device__ inline float bsum128(float v, volatile float* red){
  v += __shfl_xor(v,1);  v += __shfl_xor(v,2);  v += __shfl_xor(v,4);
  v += __shfl_xor(v,8);  v += __shfl_xor(v,16); v += __shfl_xor(v,32);
  int tid = threadIdx.x;
  if ((tid & 63) == 0) red[tid>>6] = v;
  __syncthreads();
  float s = red[0] + red[1];
  __syncthreads();
  return s;
}

// ---------------- inner TIT (one block per bt, 128 threads) ----------------
// also sums the NZ patch-gemm partial slabs (split-K reduce fused here)
__global__ __launch_bounds__(128) void inner_tit(
  const float* __restrict__ part, const float* __restrict__ ctok,
  const float* __restrict__ t_in, const float* __restrict__ in_b,
  const float* __restrict__ t_out, const float* __restrict__ out_b,
  const float* __restrict__ g1, const float* __restrict__ b1_,
  const float* __restrict__ g2, const float* __restrict__ b2_,
  const float* __restrict__ t_f1, const float* __restrict__ fb1,
  const float* __restrict__ t_f2, const float* __restrict__ fb2,
  float* __restrict__ semb)
{
  int bt = blockIdx.x, e = threadIdx.x;
  __shared__ float xs[2][128], hs[2][128], qs[2][128], ks2[2][128], vs[2][128];
  __shared__ float red[2];
  {
    float acc = 0;
    #pragma unroll
    for (int z=0; z<NZ; ++z) acc += part[(size_t)z*NBT*EE + bt*128 + e];
    xs[0][e] = ctok[e];
    xs[1][e] = acc;
  }
  __syncthreads();
  for (int t=0;t<2;t++){             // LN1
    float xv = xs[t][e];
    float m = bsum128(xv, red)*(1.f/128.f);
    float d = xv - m;
    float var = bsum128(d*d, red)*(1.f/128.f);
    hs[t][e] = d*rsqrtf(var+1e-5f)*g1[e] + b1_[e];
  }
  __syncthreads();
  for (int t=0;t<2;t++){             // qkv
    float aq=in_b[e], ak=in_b[128+e], av=in_b[256+e];
    for (int kk=0;kk<128;kk++){
      float h = hs[t][kk];
      aq += h*t_in[kk*384+e]; ak += h*t_in[kk*384+128+e]; av += h*t_in[kk*384+256+e];
    }
    qs[t][e]=aq; ks2[t][e]=ak; vs[t][e]=av;
  }
  __syncthreads();
  const float sc = 0.08838834764831845f;   // 1/sqrt(128)
  float s00 = bsum128(qs[0][e]*ks2[0][e], red)*sc;
  float s01 = bsum128(qs[0][e]*ks2[1][e], red)*sc;
  float s10 = bsum128(qs[1][e]*ks2[0][e], red)*sc;
  float s11 = bsum128(qs[1][e]*ks2[1][e], red)*sc;
  {
    float m0 = fmaxf(s00,s01), p0=expf(s00-m0), p1=expf(s01-m0), iv=1.f/(p0+p1);
    hs[0][e] = (p0*vs[0][e] + p1*vs[1][e])*iv;
    float m1 = fmaxf(s10,s11), r0=expf(s10-m1), r1=expf(s11-m1), iw=1.f/(r0+r1);
    hs[1][e] = (r0*vs[0][e] + r1*vs[1][e])*iw;
  }
  __syncthreads();
  for (int t=0;t<2;t++){             // out-proj + residual
    float o = out_b[e];
    for (int kk=0;kk<128;kk++) o += hs[t][kk]*t_out[kk*128+e];
    xs[t][e] += o;
  }
  __syncthreads();
  for (int t=0;t<2;t++){             // LN2 -> qs
    float xv = xs[t][e];
    float m = bsum128(xv, red)*(1.f/128.f);
    float d = xv - m;
    float var = bsum128(d*d, red)*(1.f/128.f);
    qs[t][e] = d*rsqrtf(var+1e-5f)*g2[e] + b2_[e];
  }
  __syncthreads();
  for (int t=0;t<2;t++){             // FFN1 (relu) -> hs
    float a = fb1[e];
    for (int kk=0;kk<128;kk++) a += qs[t][kk]*t_f1[kk*128+e];
    hs[t][e] = fmaxf(a, 0.f);
  }
  __syncthreads();
  for (int t=0;t<2;t++){             // FFN2 + residual
    float a = fb2[e];
    for (int kk=0;kk<128;kk++) a += hs[t][kk]*t_f2[kk*128+e];
    xs[t][e] += a;
  }
  semb[bt*128+e] = xs[0][e];
}

// ---------------- token interleave + positional ----------------------------
__global__ __launch_bounds__(256) void build_tok(
  const float* __restrict__ semb, const float* __restrict__ rtgs,
  const int* __restrict__ actions, const int* __restrict__ tsteps,
  const float* __restrict__ ret_w, const float* __restrict__ ret_b,
  const float* __restrict__ act_tab, const float* __restrict__ pos_emb,
  const float* __restrict__ gpos, float* __restrict__ x)
{
  int idx = blockIdx.x*256 + threadIdx.x;
  if (idx >= NS*EE) return;
  int e = idx & 127, s = idx >> 7;
  int b = s / LTK, p = s - b*LTK;
  int t = p/3, m = p - 3*t;
  float tok;
  if      (m == 0) tok = tanhf(rtgs[b*NT+t]*ret_w[e] + ret_b[e]);
  else if (m == 1) tok = semb[(b*NT+t)*128 + e];
  else             tok = tanhf(act_tab[actions[b*NT+t+1]*128 + e]);
  x[idx] = tok + gpos[(size_t)tsteps[b]*128 + e] + pos_emb[p*128 + e];
}

// ------- outer causal attention: one block per (b,h), fully parallel -------
// qkv is (NS,384) fp32: q at col 0, k at 128, v at 256
__global__ __launch_bounds__(256) void attn_k(
  const float* __restrict__ qkv, ushort_t* __restrict__ y)
{
  __shared__ float qs[LTK][17], ks[LTK][17], vs[LTK][17];
  __shared__ float ps[LTK][91];
  int b = blockIdx.x >> 3, h = blockIdx.x & 7;
  int tid = threadIdx.x;
  for (int i = tid; i < LTK*16; i += 256){
    int rr = i >> 4, d = i & 15;
    size_t g = (size_t)(b*LTK+rr)*384 + h*16 + d;
    qs[rr][d] = qkv[g]; ks[rr][d] = qkv[g+128]; vs[rr][d] = qkv[g+256];
  }
  __syncthreads();
  for (int i = tid; i < LTK*LTK; i += 256){     // scores (lower triangle)
    int t = i/LTK, u = i - t*LTK;
    if (u <= t){
      float s = 0;
      #pragma unroll
      for (int d=0;d<16;d++) s += qs[t][d]*ks[u][d];
      ps[t][u] = s*0.25f;                       // 1/sqrt(16)
    }
  }
  __syncthreads();
  if (tid < LTK){                                // row softmax
    int t = tid;
    float mx = -1e30f;
    for (int u=0;u<=t;u++) mx = fmaxf(mx, ps[t][u]);
    float l = 0;
    for (int u=0;u<=t;u++){ float p = __expf(ps[t][u]-mx); ps[t][u]=p; l+=p; }
    ps[t][89] = 1.0f/l;
  }
  __syncthreads();
  for (int i = tid; i < LTK*16; i += 256){       // PV
    int t = i >> 4, d = i & 15;
    float a = 0;
    for (int u=0; u<=t; ++u) a += ps[t][u]*vs[u][d];
    y[(size_t)(b*LTK+t)*128 + h*16 + d] = f2bf(a*ps[t][89]);
  }
}

// ---------------- final LN + head on the 1920 state tokens -----------------
__global__ __launch_bounds__(128) void head_k(
  const float* __restrict__ x, const float* __restrict__ g,
  const float* __restrict__ bb, const float* __restrict__ hw,
  float* __restrict__ out)
{
  __shared__ float red[2];
  __shared__ float hsm[128];
  int bt = blockIdx.x;
  int b = bt/NT, t = bt - b*NT;
  int e = threadIdx.x;
  const float* row = x + (size_t)(b*LTK + 3*t + 1)*128;
  float xv = row[e];
  float m = bsum128(xv, red)*(1.f/128.f);
  float d = xv - m;
  float var = bsum128(d*d, red)*(1.f/128.f);
  hsm[e] = d*rsqrtf(var+1e-5f)*g[e] + bb[e];
  __syncthreads();
  int wv = e >> 6, ln = e & 63;
  for (int o = wv*9; o < wv*9+9; ++o){
    float s = hsm[ln]*hw[o*128+ln] + hsm[ln+64]*hw[o*128+ln+64];
    s += __shfl_xor(s,1); s += __shfl_xor(s,2); s += __shfl_xor(s,4);
    s += __shfl_xor(s,8); s += __shfl_xor(s,16); s += __shfl_xor(s,32);
    if (ln == 0) out[(size_t)(b*NT+t)*NV + o] = s;
  }
}

// ===========================================================================
extern "C" void kernel_launch(void* const* d_in, const int* in_sizes, int n_in,
                              void* d_out, int out_size, void* d_ws, size_t ws_size,
                              hipStream_t stream)
{
  const float* states  = (const float*)d_in[0];
  const int*   actions = (const int*)  d_in[1];
  const float* rtgs    = (const float*)d_in[2];
  const int*   tsteps  = (const int*)  d_in[3];
  const float* conv_w  = (const float*)d_in[4];
  const float* ctok    = (const float*)d_in[5];
  const float* in_w    = (const float*)d_in[6];
  const float* in_b    = (const float*)d_in[7];
  const float* out_w   = (const float*)d_in[8];
  const float* out_b   = (const float*)d_in[9];
  const float* i1g     = (const float*)d_in[10];
  const float* i1b     = (const float*)d_in[11];
  const float* i2g     = (const float*)d_in[12];
  const float* i2b     = (const float*)d_in[13];
  const float* fw1     = (const float*)d_in[14];
  const float* fb1     = (const float*)d_in[15];
  const float* fw2     = (const float*)d_in[16];
  const float* fb2     = (const float*)d_in[17];
  const float* ret_w   = (const float*)d_in[18];
  const float* ret_b   = (const float*)d_in[19];
  const float* act_tab = (const float*)d_in[20];
  const float* pos_emb = (const float*)d_in[21];
  const float* gpos    = (const float*)d_in[22];
  const float* ln1g    = (const float*)d_in[23];
  const float* ln1b    = (const float*)d_in[24];
  const float* Wq      = (const float*)d_in[25];
  const float* bq      = (const float*)d_in[26];
  const float* Wk      = (const float*)d_in[27];
  const float* bk      = (const float*)d_in[28];
  const float* Wv      = (const float*)d_in[29];
  const float* bv      = (const float*)d_in[30];
  const float* Wo      = (const float*)d_in[31];
  const float* bo      = (const float*)d_in[32];
  const float* ln2g    = (const float*)d_in[33];
  const float* ln2b    = (const float*)d_in[34];
  const float* W1      = (const float*)d_in[35];
  const float* b1      = (const float*)d_in[36];
  const float* W2      = (const float*)d_in[37];
  const float* b2      = (const float*)d_in[38];
  const float* lnfg    = (const float*)d_in[39];
  const float* lnfb    = (const float*)d_in[40];
  const float* head_w  = (const float*)d_in[41];

  char* w = (char*)d_ws;
  size_t off = 0;
  auto alloc = [&](size_t bytes)->char* {
    char* p = w + off; off += (bytes + 255) & ~(size_t)255; return p;
  };
  float*    part  = (float*)   alloc((size_t)NZ*NBT*EE*4);
  float*    semb  = (float*)   alloc((size_t)NBT*EE*4);
  float*    x     = (float*)   alloc((size_t)NS*EE*4);
  float*    qkvb  = (float*)   alloc((size_t)NS*384*4);
  ushort_t* yb    = (ushort_t*)alloc((size_t)NS*EE*2);
  ushort_t* f1b_  = (ushort_t*)alloc((size_t)NS*LL4*2);
  ushort_t* cwb   = (ushort_t*)alloc((size_t)EE*KP*2);
  ushort_t* Wqkvb = (ushort_t*)alloc((size_t)NLY*384*128*2);
  ushort_t* Wob   = (ushort_t*)alloc((size_t)NLY*128*128*2);
  ushort_t* W1b   = (ushort_t*)alloc((size_t)NLY*512*128*2);
  ushort_t* W2b   = (ushort_t*)alloc((size_t)NLY*128*512*2);
  float*    t_in  = (float*)   alloc(384*128*4);
  float*    t_out = (float*)   alloc(128*128*4);
  float*    t_f1  = (float*)   alloc(128*128*4);
  float*    t_f2  = (float*)   alloc(128*128*4);
  float*    bqkv  = (float*)   alloc(NLY*384*4);
  (void)in_sizes; (void)n_in; (void)out_size; (void)ws_size;

  wcvt<<<4680,256,0,stream>>>(conv_w,Wq,Wk,Wv,Wo,W1,W2, cwb,Wqkvb,Wob,W1b,W2b);
  tinner<<<192,256,0,stream>>>(in_w,out_w,fw1,fw2, bq,bk,bv,
                               t_in,t_out,t_f1,t_f2, bqkv);
  patch_gemm<<<dim3(60,1,NZ),256,0,stream>>>(states, cwb, part);
  inner_tit<<<NBT,128,0,stream>>>(part, ctok, t_in, in_b, t_out, out_b,
                                  i1g,i1b,i2g,i2b, t_f1,fb1, t_f2,fb2, semb);
  build_tok<<<2848,256,0,stream>>>(semb, rtgs, actions, tsteps, ret_w, ret_b,
                                   act_tab, pos_emb, gpos, x);
  for (int i=0;i<NLY;i++){
    gemm_k<128,false,true,0,false,false><<<dim3(178,3),256,0,stream>>>(
      x, Wqkvb+(size_t)i*49152, bqkv+(size_t)i*384, ln1g+i*128, ln1b+i*128,
      qkvb, nullptr, nullptr, 384);
    attn_k<<<512,256,0,stream>>>(qkvb, yb);
    gemm_k<128,true,false,0,true,false><<<dim3(178,1),256,0,stream>>>(
      yb, Wob+(size_t)i*16384, bo+i*128, nullptr, nullptr, x, nullptr, x, 128);
    gemm_k<128,false,true,1,false,true><<<dim3(178,4),256,0,stream>>>(
      x, W1b+(size_t)i*65536, b1+i*512, ln2g+i*128, ln2b+i*128, nullptr, f1b_, nullptr, 512);
    gemm_k<512,true,false,0,true,false><<<dim3(178,1),256,0,stream>>>(
      f1b_, W2b+(size_t)i*65536, b2+i*128, nullptr, nullptr, x, nullptr, x, 128);
  }
  head_k<<<NBT,128,0,stream>>>(x, lnfg, lnfb, head_w, (float*)d_out);
}